// Round 11
// baseline (588.467 us; speedup 1.0000x reference)
//
#include <hip/hip_runtime.h>

// ---------------------------------------------------------------------------
// TemporalAttnLayer: B=256, T=64, M=256, H=256
//
// Round-23 = Round-22 (557 us best: f16-fdot2 gates, fp8-shaped loop) with
// ONE surgical change: x1 runs on ALL 16 waves (K-quarter split, 128 MACs
// per thread), halving the serial-chain head.
//  - Gate waves: x1 quarter -> flagX add -> straight into gates (gates do
//    NOT consume xq, so no wait). Gate placement/overlap = r22 exactly
//    (r20's regression was gate serialization, not the K4 split).
//  - Score waves: x1 quarter -> flagX(16) wait -> scores sum 4 quarters.
//  - Everything else byte-identical to r22 (flagE=5, LSTM threads 0-255,
//    single barrier, f16 gates, fp8 W_d in 128 KB LDS).
// Cost: scores read 5 float4/g (was 3); bank conflicts ~2x (r20 data).
// Spill gate: WRITE > 15 MB = abort. Neutral => x1 not exposed => plateau.
// ---------------------------------------------------------------------------

#define Bx 256
#define Tx 64
#define Mx 256
#define Hx 256
#define NT 1024
#define XS 20     // swizzle chunk stride (floats) for xq/vd

typedef unsigned int  uint;
typedef unsigned short ushort;
typedef _Float16 h2  __attribute__((ext_vector_type(2)));
typedef float    f2v __attribute__((ext_vector_type(2)));

__device__ __forceinline__ float4 ld4(const float* p) { return *(const float4*)p; }
__device__ __forceinline__ float h2f(ushort s) {
  union { ushort s; _Float16 h; } c; c.s = s; return (float)c.h;
}
__device__ __forceinline__ ushort f2h(float f) {
  union { _Float16 h; ushort s; } c; c.h = (_Float16)f; return c.s;
}
__device__ __forceinline__ uint pk2(float a, float b) {
  return (uint)f2h(a) | ((uint)f2h(b) << 16);
}

#if defined(__has_builtin)
#if __has_builtin(__builtin_amdgcn_rcpf)
#define RCPF(x) __builtin_amdgcn_rcpf(x)
#endif
#if __has_builtin(__builtin_amdgcn_fdot2)
#define HAVE_FDOT2 1
#endif
#if __has_builtin(__builtin_amdgcn_cvt_pk_f32_fp8) && __has_builtin(__builtin_amdgcn_cvt_pk_fp8_f32)
#define HAVE_FP8 1
#endif
#endif
#ifndef RCPF
#define RCPF(x) (1.0f / (x))
#endif

__device__ __forceinline__ float tanh_fast(float x) {
  float e2 = __expf(2.0f * x);
  return 1.0f - 2.0f * RCPF(e2 + 1.0f);
}
// arg already pre-doubled upstream: tanh(x) where z2 = 2x
__device__ __forceinline__ float tanh_pre(float z2) {
  return 1.0f - 2.0f * RCPF(__expf(z2) + 1.0f);
}
__device__ __forceinline__ float sigm(float x) {
  return RCPF(1.0f + __expf(-x));
}
__device__ __forceinline__ float wave_sum(float v) {
  #pragma unroll
  for (int o = 1; o < 64; o <<= 1) v += __shfl_xor(v, o, 64);
  return v;
}
__device__ __forceinline__ int xsw(int m) { return (m >> 4) * XS + (m & 15); }

// f16 pair dot: acc += w.lo*a.lo + w.hi*a.hi (single v_dot2_f32_f16)
__device__ __forceinline__ float dot2u(uint w, uint a, float acc) {
#ifdef HAVE_FDOT2
  h2 W = __builtin_bit_cast(h2, w);
  h2 A = __builtin_bit_cast(h2, a);
  return __builtin_amdgcn_fdot2(W, A, acc, false);
#else
  return acc + h2f((ushort)w) * h2f((ushort)a)
             + h2f((ushort)(w >> 16)) * h2f((ushort)(a >> 16));
#endif
}

// ---- fp8 e4m3fn encode/decode (HW path + software fallback) ----
__device__ __forceinline__ uint sw8(float f) {
  union { float f; uint u; } c; c.f = f;
  uint s = (c.u >> 31) << 7;
  float a = fabsf(f);
  if (!(a >= 0.0009765625f)) return s;
  if (a >= 448.f) return s | 0x7e;
  int e = (int)((c.u >> 23) & 0xff) - 127;
  if (e < -6) { int q = (int)(a * 512.f + 0.5f); return s | (uint)q; }
  uint m = ((c.u & 0x7fffff) + 0x80000) >> 20;
  if (m == 8) { m = 0; ++e; }
  if (e > 8) return s | 0x7e;
  return s | ((uint)(e + 7) << 3) | m;
}
__device__ __forceinline__ float sw8d(uint b) {
  uint s = b >> 7, e = (b >> 3) & 0xf, m = b & 7;
  float v;
  if (e) { union { uint u; float f; } c; c.u = ((e + 120u) << 23) | (m << 20); v = c.f; }
  else v = (float)m * 0.001953125f;
  return s ? -v : v;
}
__device__ __forceinline__ uint pk_fp8x4(float w0, float w1, float w2, float w3) {
#ifdef HAVE_FP8
  int u = 0;
  u = __builtin_amdgcn_cvt_pk_fp8_f32(w0, w1, u, false);
  u = __builtin_amdgcn_cvt_pk_fp8_f32(w2, w3, u, true);
  return (uint)u;
#else
  return sw8(w0) | (sw8(w1) << 8) | (sw8(w2) << 16) | (sw8(w3) << 24);
#endif
}
template <bool HI>
__device__ __forceinline__ f2v dec2(uint w) {
#ifdef HAVE_FP8
  return __builtin_amdgcn_cvt_pk_f32_fp8((int)w, HI);
#else
  uint b0 = HI ? ((w >> 16) & 0xffu) : (w & 0xffu);
  uint b1 = HI ? (w >> 24) : ((w >> 8) & 0xffu);
  return f2v{sw8d(b0), sw8d(b1)};
#endif
}
__device__ __forceinline__ f2v dotq(uint w, float4 a, f2v acc) {
  acc += dec2<false>(w) * f2v{a.x, a.y};
  acc += dec2<true>(w)  * f2v{a.z, a.w};
  return acc;
}

// ---------------------------------------------------------------------------
// Pack kernel (identical to r22). WhhH[c*1024+j] = f16 of W_hh[j][8c..8c+7].
// ---------------------------------------------------------------------------
__global__ __launch_bounds__(256)
void pack_weights(const float* __restrict__ W_d,
                  const float* __restrict__ W_hh,
                  const float* __restrict__ U_d,
                  const float* __restrict__ W_y,
                  uint4* __restrict__ WhhH,
                  uint4* __restrict__ Wd8q,
                  uint4* __restrict__ Ud8,
                  float* __restrict__ Wyt) {
  const int blk = blockIdx.x, tid = threadIdx.x;
  if (blk < 32) {                        // WhhH chunk c: cols 8c..8c+7
    const int c = blk;
    #pragma unroll
    for (int q = 0; q < 4; ++q) {
      const int j = tid + 256 * q;
      const float* wr = W_hh + (size_t)j * 256 + 8 * c;
      float4 a = ld4(wr), b = ld4(wr + 4);
      WhhH[c * 1024 + j] = uint4{pk2(a.x, a.y), pk2(a.z, a.w),
                                 pk2(b.x, b.y), pk2(b.z, b.w)};
    }
  } else if (blk < 64) {                 // Wd8q
    const int k16 = blk - 32;
    const float* wr = W_d + (size_t)tid * 512 + 16 * k16;
    float4 a = ld4(wr), b = ld4(wr + 4), c = ld4(wr + 8), d = ld4(wr + 12);
    uint4 u;
    u.x = pk_fp8x4(16.f * a.x, 16.f * a.y, 16.f * a.z, 16.f * a.w);
    u.y = pk_fp8x4(16.f * b.x, 16.f * b.y, 16.f * b.z, 16.f * b.w);
    u.z = pk_fp8x4(16.f * c.x, 16.f * c.y, 16.f * c.z, 16.f * c.w);
    u.w = pk_fp8x4(16.f * d.x, 16.f * d.y, 16.f * d.z, 16.f * d.w);
    Wd8q[k16 * 256 + tid] = u;
  } else if (blk < 96) {                 // Ud8 (f16, x2 folded for tanh)
    const int m8 = blk - 64;
    float4 a = ld4(U_d + (size_t)tid * 256 + 8 * m8);
    float4 b = ld4(U_d + (size_t)tid * 256 + 8 * m8 + 4);
    Ud8[m8 * 256 + tid] = uint4{pk2(2.f * a.x, 2.f * a.y), pk2(2.f * a.z, 2.f * a.w),
                                pk2(2.f * b.x, 2.f * b.y), pk2(2.f * b.z, 2.f * b.w)};
  } else {                               // Wyt transpose
    const int k0 = (blk - 96) * 4;
    float4 w = ld4(W_y + (size_t)tid * 512 + k0);
    Wyt[(k0 + 0) * 256 + tid] = w.x;
    Wyt[(k0 + 1) * 256 + tid] = w.y;
    Wyt[(k0 + 2) * 256 + tid] = w.z;
    Wyt[(k0 + 3) * 256 + tid] = w.w;
  }
}

// ---------------------------------------------------------------------------
// Main kernel: one 1024-thread wg per batch element.
// Per step: ALL 16 waves x1 K-quarter -> flagX add -> {gate waves: f16
// fdot2 gates (no flagX wait) | score waves: wait flagX=16 -> scores (sum
// 4 quarters) -> flagL -> wave 8 softmax -> flagE} -> LSTM (threads 0-255,
// flagE=5) -> single barrier.
// ---------------------------------------------------------------------------
__global__ __launch_bounds__(NT, 1)
void fused(const float* __restrict__ enc,      // (T,B,M)
           const float* __restrict__ yv,       // (B,T,1)
           const float* __restrict__ b_Wd,     // (M)
           const float* __restrict__ v_d,      // (1,M)
           const float* __restrict__ w_tilda,  // (1,M+1)
           const float* __restrict__ b_wt,     // (1)
           const float* __restrict__ W_ih,     // (4H,1)
           const float* __restrict__ b_ih,     // (4H)
           const float* __restrict__ b_hh,     // (4H)
           const float* __restrict__ b_Wy,     // (H)
           const float* __restrict__ v_y,      // (1,H)
           const float* __restrict__ b_vy,     // (1)
           const uint4* __restrict__ WhhH,
           const uint4* __restrict__ Wd8q,
           const uint4* __restrict__ Ud8,
           const float* __restrict__ Wyt,
           ushort* __restrict__ Y1,            // (B,T,M) f16 scratch
           float* __restrict__ out)            // (B,1)
{
  extern __shared__ __align__(16) uint4 wdl[];      // 8192 uint4 = 128 KB W_d
  __shared__ __align__(16) float dsp_s[2 * Hx];     // [d|sp] f32 (x1 bcast)
  __shared__ __align__(16) ushort dsph_s[Hx];       // d packed f16 (gates)
  __shared__ __align__(16) float xq_s[4 * 16 * XS]; // x1 K-quarter partials
  __shared__ __align__(16) float vd_s[16 * XS];     // v_d swizzled
  __shared__ float gates_s[1024];                   // f,o gates; epi partials
  __shared__ float dcfin_s[2 * Hx];                 // [d|c] fp32 (epilogue)
  __shared__ float l_s[Tx];
  __shared__ uint  beta2_s[Tx / 2];                 // beta packed f16 (t=63)
  __shared__ float e_s[Tx];                         // E_t
  __shared__ float red_s[4];
  __shared__ float ytil_s;
  __shared__ unsigned flagX, flagL, flagE;

  const int b   = blockIdx.x;
  const int tid = threadIdx.x;     // 0..1023
  const int h   = tid & 255;
  const int p   = tid >> 8;        // 0..3
  const int mq  = tid & 255;       // x1: output m
  const int qq  = tid >> 8;        // x1: K-quarter 0..3
  const size_t BM = (size_t)Bx * Mx;

  // ---- stage 0: W_d -> LDS (one-time), params, state, flags ----
  #pragma unroll
  for (int i = 0; i < 8; ++i) wdl[i * NT + tid] = Wd8q[i * NT + tid];
  if (tid < 256) vd_s[xsw(tid)] = v_d[tid];
  if (tid < 512) dsp_s[tid] = 0.0f;
  if (tid < 256) dsph_s[tid] = 0;
  if (tid == 0) { flagX = 0u; flagL = 0u; flagE = 0u; }

  float bj0 = 0.f, bj1 = 0.f;                  // gate waves
  if (tid < 512) { bj0 = b_ih[tid] + b_hh[tid]; bj1 = b_ih[tid + 512] + b_hh[tid + 512]; }
  float bWd_r = 0.f;                           // x1 quarter-0 threads (x2 fold)
  if (tid < 256) bWd_r = 2.0f * b_Wd[tid];
  float wih0 = 0.f, wih1 = 0.f, wih2 = 0.f, wih3 = 0.f;  // LSTM: threads 0-255
  if (tid < 256) {
    wih0 = W_ih[tid]; wih1 = W_ih[tid + 256]; wih2 = W_ih[tid + 512]; wih3 = W_ih[tid + 768];
  }
  float yv_r = 0.f;                            // softmax wave
  if (tid >= 512 && tid < 576) yv_r = yv[b * Tx + (tid - 512)];
  const float wty = w_tilda[Mx];
  const float bwt = b_wt[0];

  // ---- stage 0b: E_t = sum_m w~_m enc[t][b][m] (one-time) ----
  if (tid < Tx) {
    const float* er = enc + (size_t)tid * BM + (size_t)b * Mx;
    float acc = 0.0f;
    for (int m = 0; m < Mx; m += 4) {
      float4 e4 = ld4(er + m);
      float4 w4 = ld4(w_tilda + m);
      acc += e4.x * w4.x + e4.y * w4.y + e4.z * w4.z + e4.w * w4.w;
    }
    e_s[tid] = acc;
  }

  // ---- stage 1: Y1[b] = enc[b] @ (2*U_d)^T (f16 weights) ----
  {
    const int n = h;
    const float* eb = enc + (size_t)b * Mx;
    for (int tb = p * 16; tb < p * 16 + 16; tb += 8) {
      f2v acc2[8];
      #pragma unroll
      for (int j = 0; j < 8; ++j) acc2[j] = f2v{0.f, 0.f};
      #pragma unroll 2
      for (int m8 = 0; m8 < 32; ++m8) {
        uint4 u = Ud8[m8 * 256 + n];
        f2v w01 = f2v{h2f((ushort)u.x), h2f((ushort)(u.x >> 16))};
        f2v w23 = f2v{h2f((ushort)u.y), h2f((ushort)(u.y >> 16))};
        f2v w45 = f2v{h2f((ushort)u.z), h2f((ushort)(u.z >> 16))};
        f2v w67 = f2v{h2f((ushort)u.w), h2f((ushort)(u.w >> 16))};
        #pragma unroll
        for (int j = 0; j < 8; ++j) {
          const float* ep = eb + (size_t)(tb + j) * BM + 8 * m8;
          float4 ea = ld4(ep), eb4 = ld4(ep + 4);
          acc2[j] += f2v{ea.x, ea.y} * w01;
          acc2[j] += f2v{ea.z, ea.w} * w23;
          acc2[j] += f2v{eb4.x, eb4.y} * w45;
          acc2[j] += f2v{eb4.z, eb4.w} * w67;
        }
      }
      #pragma unroll
      for (int j = 0; j < 8; ++j)
        Y1[((size_t)b * Tx + tb + j) * Mx + n] = f2h(acc2[j].x + acc2[j].y);
    }
  }
  __syncthreads();  // S1: wdl, dsp_s, dsph_s, vd_s, e_s, flags, Y1 ready

  // e_s row for the softmax wave: 1 register
  float e_r = 0.0f;
  if (tid >= 512 && tid < 576) e_r = e_s[tid - 512];

  float sp_reg = 0.0f;   // LSTM state: threads 0-255

  for (int t = 0; t < Tx; ++t) {
    // ---- Y1 row segment prefetch (score waves; hidden under x1) ----
    uint4 yq0, yq1, yq2, yq3;
    if (tid >= 512) {
      const int idx = tid - 512;
      const int tq = idx >> 3, lq = idx & 7;
      const ushort* y1r = Y1 + ((size_t)b * Tx + tq) * Mx + lq * 32;
      yq0 = *(const uint4*)(y1r);
      yq1 = *(const uint4*)(y1r + 8);
      yq2 = *(const uint4*)(y1r + 16);
      yq3 = *(const uint4*)(y1r + 24);
    }

    // ===== x1: ALL 16 waves, K-quarter each (128 MACs, fp8 LDS) =====
    {
      f2v xa2 = f2v{0.f, 0.f};
      const uint4* xp = wdl + mq + (qq * 8) * 256;   // chunks qq*8..qq*8+7
      #pragma unroll
      for (int i = 0; i < 8; ++i) {
        uint4 u = xp[i * 256];
        const float4* ap = (const float4*)dsp_s + 4 * (qq * 8 + i);  // bcast
        float4 a0 = ap[0], a1 = ap[1], a2 = ap[2], a3 = ap[3];
        xa2 = dotq(u.x, a0, xa2); xa2 = dotq(u.y, a1, xa2);
        xa2 = dotq(u.z, a2, xa2); xa2 = dotq(u.w, a3, xa2);
      }
      // x2 folded for tanh: scale 0.125, bWd pre-doubled
      xq_s[qq * (16 * XS) + xsw(mq)] = (xa2.x + xa2.y) * 0.125f
                                     + (qq == 0 ? bWd_r : 0.0f);
    }
    __threadfence_block();
    if ((tid & 63) == 0)
      __hip_atomic_fetch_add(&flagX, 1u, __ATOMIC_RELEASE, __HIP_MEMORY_SCOPE_WORKGROUP);

    float gi = 0.0f, gg = 0.0f;   // own i,g gates (threads 0-255 keep in regs)
    if (tid < 512) {
      // ===== GATE WAVES: j=tid, j+512 via f16 fdot2 (no flagX wait) =====
      float ga0 = 0.f, ga1 = 0.f, gb0 = 0.f, gb1 = 0.f;
      const uint4* wp  = WhhH + tid;
      const uint4* adp = (const uint4*)dsph_s;       // 32 uint4 broadcast
      #pragma unroll 2
      for (int c = 0; c < 32; ++c) {
        uint4 wa = wp[c * 1024];
        uint4 wb = wp[c * 1024 + 512];
        uint4 a  = adp[c];                           // d[8c .. 8c+7] f16
        ga0 = dot2u(wa.x, a.x, ga0); ga1 = dot2u(wa.y, a.y, ga1);
        ga0 = dot2u(wa.z, a.z, ga0); ga1 = dot2u(wa.w, a.w, ga1);
        gb0 = dot2u(wb.x, a.x, gb0); gb1 = dot2u(wb.y, a.y, gb1);
        gb0 = dot2u(wb.z, a.z, gb0); gb1 = dot2u(wb.w, a.w, gb1);
      }
      gi = ga0 + ga1 + bj0;
      gg = gb0 + gb1 + bj1;
      if (tid >= 256) {
        // publish f (j=tid) and o (j=tid+512) gates for the LSTM threads
        gates_s[tid]       = gi;
        gates_s[tid + 512] = gg;
        __threadfence_block();
        if ((tid & 63) == 0)
          __hip_atomic_fetch_add(&flagE, 1u, __ATOMIC_RELEASE, __HIP_MEMORY_SCOPE_WORKGROUP);
      }
    } else {
      // ===== SCORE WAVES =====
      const int idx = tid - 512;               // 0..511
      const int tq = idx >> 3, lq = idx & 7;
      const unsigned tgtX = 16u * (unsigned)(t + 1);
      while (__hip_atomic_load(&flagX, __ATOMIC_ACQUIRE, __HIP_MEMORY_SCOPE_WORKGROUP) < tgtX) {}

      // scores: 8 lanes/query, lane covers 32 m's; sum 4 xq quarters
      {
        float ps = 0.0f;
        uint yy[8] = {yq0.x, yq0.y, yq0.z, yq0.w, yq1.x, yq1.y, yq1.z, yq1.w};
        uint zz[8] = {yq2.x, yq2.y, yq2.z, yq2.w, yq3.x, yq3.y, yq3.z, yq3.w};
        #pragma unroll
        for (int g = 0; g < 8; ++g) {
          const int c   = 2 * lq + (g >> 2);
          const int off = c * XS + 4 * (g & 3);
          float4 x0 = *(const float4*)(xq_s + off);
          float4 x1 = *(const float4*)(xq_s + 320 + off);
          float4 x2 = *(const float4*)(xq_s + 640 + off);
          float4 x3 = *(const float4*)(xq_s + 960 + off);
          float4 vv = *(const float4*)(vd_s + off);
          uint ya = (g < 4) ? yy[2 * g] : zz[2 * (g - 4)];
          uint yb = (g < 4) ? yy[2 * g + 1] : zz[2 * (g - 4) + 1];
          ps += tanh_pre(x0.x + x1.x + x2.x + x3.x + h2f((ushort)ya)) * vv.x
              + tanh_pre(x0.y + x1.y + x2.y + x3.y + h2f((ushort)(ya >> 16))) * vv.y
              + tanh_pre(x0.z + x1.z + x2.z + x3.z + h2f((ushort)yb)) * vv.z
              + tanh_pre(x0.w + x1.w + x2.w + x3.w + h2f((ushort)(yb >> 16))) * vv.w;
        }
        ps += __shfl_xor(ps, 1, 64);
        ps += __shfl_xor(ps, 2, 64);
        ps += __shfl_xor(ps, 4, 64);
        if (lq == 0) l_s[tq] = ps;
      }
      __threadfence_block();
      if ((tid & 63) == 0)
        __hip_atomic_fetch_add(&flagL, 1u, __ATOMIC_RELEASE, __HIP_MEMORY_SCOPE_WORKGROUP);

      if (idx < 64) {
        // merged softmax+ytil (wave 8): |l| <= ~10 so no max-sub needed;
        // one interleaved {den,num} reduction; beta only at t==63.
        __builtin_amdgcn_s_setprio(1);
        const unsigned tgtL = 8u * (unsigned)(t + 1);
        while (__hip_atomic_load(&flagL, __ATOMIC_ACQUIRE, __HIP_MEMORY_SCOPE_WORKGROUP) < tgtL) {}
        float e0  = __expf(l_s[idx]);
        float den = e0;
        float num = e0 * e_r;
        #pragma unroll
        for (int o = 1; o < 64; o <<= 1) {
          den += __shfl_xor(den, o, 64);
          num += __shfl_xor(num, o, 64);
        }
        if (t == Tx - 1) {
          float beta = e0 * RCPF(den);
          float bn = __shfl_xor(beta, 1, 64);
          if (!(idx & 1)) beta2_s[idx >> 1] = pk2(beta, bn);
        }
        if (idx == t) ytil_s = num * RCPF(den) + wty * yv_r + bwt;
        __threadfence_block();
        if (idx == 0)
          __hip_atomic_fetch_add(&flagE, 1u, __ATOMIC_RELEASE, __HIP_MEMORY_SCOPE_WORKGROUP);
        __builtin_amdgcn_s_setprio(0);
      }
    }

    // ===== LSTM cell: threads 0-255 (i,g in regs; f,o + ytil via flagE) ====
    if (tid < 256) {
      const unsigned tgtE = 5u * (unsigned)(t + 1);
      while (__hip_atomic_load(&flagE, __ATOMIC_ACQUIRE, __HIP_MEMORY_SCOPE_WORKGROUP) < tgtE) {}
      __builtin_amdgcn_s_setprio(1);
      const float ytil = ytil_s;
      float fi = sigm(gi                  + ytil * wih0);
      float ff = sigm(gates_s[256 + tid]  + ytil * wih1);
      float fg = tanh_fast(gg             + ytil * wih2);
      float fo = sigm(gates_s[768 + tid]  + ytil * wih3);
      float spn = ff * sp_reg + fi * fg;
      float dn  = fo * tanh_fast(spn);
      sp_reg = spn;
      dsp_s[tid]       = dn;
      dsp_s[256 + tid] = spn;
      dsph_s[tid]      = f2h(dn);          // packed f16 d for the gate fdot2
      if (t == Tx - 1) dcfin_s[tid] = dn;
      __builtin_amdgcn_s_setprio(0);
    }
    __syncthreads();  // B_state: d/sp(t) ready (single barrier per step)
  }

  // ===== one-time context c (beta of t=63): threads >=512, 2 lanes per m ====
  if (tid >= 512) {
    const int idx = tid - 512;
    const int m = idx >> 1, q = idx & 1;
    float acc = 0.0f;
    #pragma unroll 4
    for (int j = 0; j < 32; ++j) {
      const int tt = q * 32 + j;
      uint bp = beta2_s[tt >> 1];
      float bb = (tt & 1) ? h2f((ushort)(bp >> 16)) : h2f((ushort)bp);
      acc += bb * enc[(size_t)tt * BM + (size_t)b * Mx + m];
    }
    acc += __shfl_xor(acc, 1, 64);
    if (q == 0) dcfin_s[256 + m] = acc;
  }
  __syncthreads();

  // ===== Epilogue: out[b] = v_y . (W_y @ [d|c] + b_Wy) + b_vy =====
  {
    float a = 0.0f;
    const float* wy = Wyt + h;
    for (int k = 128 * p; k < 128 * p + 128; ++k)
      a += wy[(size_t)k * 256] * dcfin_s[k];
    gates_s[p * 256 + h] = a;     // gates_s reused as epilogue partials
  }
  __syncthreads();
  if (tid < 256) {
    float aa = gates_s[h] + gates_s[256 + h] + gates_s[512 + h] + gates_s[768 + h]
             + b_Wy[h];
    float po = aa * v_y[h];
    po = wave_sum(po);
    if ((tid & 63) == 0) red_s[tid >> 6] = po;
  }
  __syncthreads();
  if (tid == 0) out[b] = red_s[0] + red_s[1] + red_s[2] + red_s[3] + b_vy[0];
}

extern "C" void kernel_launch(void* const* d_in, const int* in_sizes, int n_in,
                              void* d_out, int out_size, void* d_ws, size_t ws_size,
                              hipStream_t stream) {
  const float* enc     = (const float*)d_in[0];
  const float* yv      = (const float*)d_in[1];
  const float* W_d     = (const float*)d_in[2];
  const float* b_Wd    = (const float*)d_in[3];
  const float* U_d     = (const float*)d_in[4];
  const float* v_d     = (const float*)d_in[5];
  const float* w_tilda = (const float*)d_in[6];
  const float* b_wt    = (const float*)d_in[7];
  const float* W_ih    = (const float*)d_in[8];
  const float* W_hh    = (const float*)d_in[9];
  const float* b_ih    = (const float*)d_in[10];
  const float* b_hh    = (const float*)d_in[11];
  const float* W_y     = (const float*)d_in[12];
  const float* b_Wy    = (const float*)d_in[13];
  const float* v_y     = (const float*)d_in[14];
  const float* b_vy    = (const float*)d_in[15];
  float* outp = (float*)d_out;

  char* ws = (char*)d_ws;
  uint4* WhhH  = (uint4*)ws;                               // 512 KB f16
  uint4* Wd8q  = (uint4*)(ws + (512 << 10));               // 128 KB
  uint4* Ud8   = (uint4*)(ws + (640 << 10));               // 128 KB
  float* Wyt   = (float*)(ws + (768 << 10));               // 512 KB
  ushort* Y1   = (ushort*)(ws + (1280 << 10));             // 8 MB

  const int DYN_LDS = 128 << 10;   // W_d fp8 slab in dynamic LDS
  hipFuncSetAttribute((const void*)fused,
                      hipFuncAttributeMaxDynamicSharedMemorySize, DYN_LDS);

  hipLaunchKernelGGL(pack_weights, dim3(224), dim3(256), 0, stream,
                     W_d, W_hh, U_d, W_y, WhhH, Wd8q, Ud8, Wyt);
  hipLaunchKernelGGL(fused, dim3(Bx), dim3(NT), DYN_LDS, stream,
                     enc, yv, b_Wd, v_d, w_tilda, b_wt, W_ih, b_ih, b_hh,
                     b_Wy, v_y, b_vy, WhhH, Wd8q, Ud8, Wyt, Y1, outp);
}

// Round 12
// 573.660 us; speedup vs baseline: 1.0258x; 1.0258x over previous
//
#include <hip/hip_runtime.h>

// ---------------------------------------------------------------------------
// TemporalAttnLayer: B=256, T=64, M=256, H=256
//
// Round-24 = Round-23 (546 us rocprof best) + distributed softmax:
//  - Each score wave reduces its own 8 queries to {den,num} partials
//    (1 exp + cndmask + 6 shfl, parallel across waves, hidden behind the
//    slowest wave's scores) and publishes 2 floats + flagP (replaces flagL).
//  - Combiner thread (tid 512): wait flagP=8 -> sum 16 floats -> ytil ->
//    flagE. The old 64-wide serial softmax (LDS read + exp + 12 shfl on
//    wave 8 while 15 waves idle) is GONE from the chain.
//  - beta(t=63): lq==0 lanes save e to l_s; combiner saves den; beta packed
//    after the loop (one extra one-time barrier).
//  - E[tq] preloaded per score thread (t-invariant); yv preloaded to LDS.
// Everything else identical to r23 (K4 x1 on 16 waves, f16 fdot2 gates with
// no flagX wait, LSTM threads 0-255 via flagE=5, single barrier per step).
// Spill gate: WRITE > 15 MB = abort. Neutral => declare plateau.
// ---------------------------------------------------------------------------

#define Bx 256
#define Tx 64
#define Mx 256
#define Hx 256
#define NT 1024
#define XS 20     // swizzle chunk stride (floats) for xq/vd

typedef unsigned int  uint;
typedef unsigned short ushort;
typedef _Float16 h2  __attribute__((ext_vector_type(2)));
typedef float    f2v __attribute__((ext_vector_type(2)));

__device__ __forceinline__ float4 ld4(const float* p) { return *(const float4*)p; }
__device__ __forceinline__ float h2f(ushort s) {
  union { ushort s; _Float16 h; } c; c.s = s; return (float)c.h;
}
__device__ __forceinline__ ushort f2h(float f) {
  union { _Float16 h; ushort s; } c; c.h = (_Float16)f; return c.s;
}
__device__ __forceinline__ uint pk2(float a, float b) {
  return (uint)f2h(a) | ((uint)f2h(b) << 16);
}

#if defined(__has_builtin)
#if __has_builtin(__builtin_amdgcn_rcpf)
#define RCPF(x) __builtin_amdgcn_rcpf(x)
#endif
#if __has_builtin(__builtin_amdgcn_fdot2)
#define HAVE_FDOT2 1
#endif
#if __has_builtin(__builtin_amdgcn_cvt_pk_f32_fp8) && __has_builtin(__builtin_amdgcn_cvt_pk_fp8_f32)
#define HAVE_FP8 1
#endif
#endif
#ifndef RCPF
#define RCPF(x) (1.0f / (x))
#endif

__device__ __forceinline__ float tanh_fast(float x) {
  float e2 = __expf(2.0f * x);
  return 1.0f - 2.0f * RCPF(e2 + 1.0f);
}
// arg already pre-doubled upstream: tanh(x) where z2 = 2x
__device__ __forceinline__ float tanh_pre(float z2) {
  return 1.0f - 2.0f * RCPF(__expf(z2) + 1.0f);
}
__device__ __forceinline__ float sigm(float x) {
  return RCPF(1.0f + __expf(-x));
}
__device__ __forceinline__ float wave_sum(float v) {
  #pragma unroll
  for (int o = 1; o < 64; o <<= 1) v += __shfl_xor(v, o, 64);
  return v;
}
__device__ __forceinline__ int xsw(int m) { return (m >> 4) * XS + (m & 15); }

// f16 pair dot: acc += w.lo*a.lo + w.hi*a.hi (single v_dot2_f32_f16)
__device__ __forceinline__ float dot2u(uint w, uint a, float acc) {
#ifdef HAVE_FDOT2
  h2 W = __builtin_bit_cast(h2, w);
  h2 A = __builtin_bit_cast(h2, a);
  return __builtin_amdgcn_fdot2(W, A, acc, false);
#else
  return acc + h2f((ushort)w) * h2f((ushort)a)
             + h2f((ushort)(w >> 16)) * h2f((ushort)(a >> 16));
#endif
}

// ---- fp8 e4m3fn encode/decode (HW path + software fallback) ----
__device__ __forceinline__ uint sw8(float f) {
  union { float f; uint u; } c; c.f = f;
  uint s = (c.u >> 31) << 7;
  float a = fabsf(f);
  if (!(a >= 0.0009765625f)) return s;
  if (a >= 448.f) return s | 0x7e;
  int e = (int)((c.u >> 23) & 0xff) - 127;
  if (e < -6) { int q = (int)(a * 512.f + 0.5f); return s | (uint)q; }
  uint m = ((c.u & 0x7fffff) + 0x80000) >> 20;
  if (m == 8) { m = 0; ++e; }
  if (e > 8) return s | 0x7e;
  return s | ((uint)(e + 7) << 3) | m;
}
__device__ __forceinline__ float sw8d(uint b) {
  uint s = b >> 7, e = (b >> 3) & 0xf, m = b & 7;
  float v;
  if (e) { union { uint u; float f; } c; c.u = ((e + 120u) << 23) | (m << 20); v = c.f; }
  else v = (float)m * 0.001953125f;
  return s ? -v : v;
}
__device__ __forceinline__ uint pk_fp8x4(float w0, float w1, float w2, float w3) {
#ifdef HAVE_FP8
  int u = 0;
  u = __builtin_amdgcn_cvt_pk_fp8_f32(w0, w1, u, false);
  u = __builtin_amdgcn_cvt_pk_fp8_f32(w2, w3, u, true);
  return (uint)u;
#else
  return sw8(w0) | (sw8(w1) << 8) | (sw8(w2) << 16) | (sw8(w3) << 24);
#endif
}
template <bool HI>
__device__ __forceinline__ f2v dec2(uint w) {
#ifdef HAVE_FP8
  return __builtin_amdgcn_cvt_pk_f32_fp8((int)w, HI);
#else
  uint b0 = HI ? ((w >> 16) & 0xffu) : (w & 0xffu);
  uint b1 = HI ? (w >> 24) : ((w >> 8) & 0xffu);
  return f2v{sw8d(b0), sw8d(b1)};
#endif
}
__device__ __forceinline__ f2v dotq(uint w, float4 a, f2v acc) {
  acc += dec2<false>(w) * f2v{a.x, a.y};
  acc += dec2<true>(w)  * f2v{a.z, a.w};
  return acc;
}

// ---------------------------------------------------------------------------
// Pack kernel (identical to r22/r23).
// ---------------------------------------------------------------------------
__global__ __launch_bounds__(256)
void pack_weights(const float* __restrict__ W_d,
                  const float* __restrict__ W_hh,
                  const float* __restrict__ U_d,
                  const float* __restrict__ W_y,
                  uint4* __restrict__ WhhH,
                  uint4* __restrict__ Wd8q,
                  uint4* __restrict__ Ud8,
                  float* __restrict__ Wyt) {
  const int blk = blockIdx.x, tid = threadIdx.x;
  if (blk < 32) {                        // WhhH chunk c: cols 8c..8c+7
    const int c = blk;
    #pragma unroll
    for (int q = 0; q < 4; ++q) {
      const int j = tid + 256 * q;
      const float* wr = W_hh + (size_t)j * 256 + 8 * c;
      float4 a = ld4(wr), b = ld4(wr + 4);
      WhhH[c * 1024 + j] = uint4{pk2(a.x, a.y), pk2(a.z, a.w),
                                 pk2(b.x, b.y), pk2(b.z, b.w)};
    }
  } else if (blk < 64) {                 // Wd8q
    const int k16 = blk - 32;
    const float* wr = W_d + (size_t)tid * 512 + 16 * k16;
    float4 a = ld4(wr), b = ld4(wr + 4), c = ld4(wr + 8), d = ld4(wr + 12);
    uint4 u;
    u.x = pk_fp8x4(16.f * a.x, 16.f * a.y, 16.f * a.z, 16.f * a.w);
    u.y = pk_fp8x4(16.f * b.x, 16.f * b.y, 16.f * b.z, 16.f * b.w);
    u.z = pk_fp8x4(16.f * c.x, 16.f * c.y, 16.f * c.z, 16.f * c.w);
    u.w = pk_fp8x4(16.f * d.x, 16.f * d.y, 16.f * d.z, 16.f * d.w);
    Wd8q[k16 * 256 + tid] = u;
  } else if (blk < 96) {                 // Ud8 (f16, x2 folded for tanh)
    const int m8 = blk - 64;
    float4 a = ld4(U_d + (size_t)tid * 256 + 8 * m8);
    float4 b = ld4(U_d + (size_t)tid * 256 + 8 * m8 + 4);
    Ud8[m8 * 256 + tid] = uint4{pk2(2.f * a.x, 2.f * a.y), pk2(2.f * a.z, 2.f * a.w),
                                pk2(2.f * b.x, 2.f * b.y), pk2(2.f * b.z, 2.f * b.w)};
  } else {                               // Wyt transpose
    const int k0 = (blk - 96) * 4;
    float4 w = ld4(W_y + (size_t)tid * 512 + k0);
    Wyt[(k0 + 0) * 256 + tid] = w.x;
    Wyt[(k0 + 1) * 256 + tid] = w.y;
    Wyt[(k0 + 2) * 256 + tid] = w.z;
    Wyt[(k0 + 3) * 256 + tid] = w.w;
  }
}

// ---------------------------------------------------------------------------
// Main kernel: one 1024-thread wg per batch element.
// Per step: ALL 16 waves x1 K-quarter -> flagX add -> {gate waves: f16
// fdot2 gates (no wait) | score waves: wait flagX=16 -> scores -> per-wave
// softmax partials -> flagP; tid 512 combines -> ytil -> flagE} -> LSTM
// (threads 0-255, flagE=5) -> single barrier.
// ---------------------------------------------------------------------------
__global__ __launch_bounds__(NT, 1)
void fused(const float* __restrict__ enc,      // (T,B,M)
           const float* __restrict__ yv,       // (B,T,1)
           const float* __restrict__ b_Wd,     // (M)
           const float* __restrict__ v_d,      // (1,M)
           const float* __restrict__ w_tilda,  // (1,M+1)
           const float* __restrict__ b_wt,     // (1)
           const float* __restrict__ W_ih,     // (4H,1)
           const float* __restrict__ b_ih,     // (4H)
           const float* __restrict__ b_hh,     // (4H)
           const float* __restrict__ b_Wy,     // (H)
           const float* __restrict__ v_y,      // (1,H)
           const float* __restrict__ b_vy,     // (1)
           const uint4* __restrict__ WhhH,
           const uint4* __restrict__ Wd8q,
           const uint4* __restrict__ Ud8,
           const float* __restrict__ Wyt,
           ushort* __restrict__ Y1,            // (B,T,M) f16 scratch
           float* __restrict__ out)            // (B,1)
{
  extern __shared__ __align__(16) uint4 wdl[];      // 8192 uint4 = 128 KB W_d
  __shared__ __align__(16) float dsp_s[2 * Hx];     // [d|sp] f32 (x1 bcast)
  __shared__ __align__(16) ushort dsph_s[Hx];       // d packed f16 (gates)
  __shared__ __align__(16) float xq_s[4 * 16 * XS]; // x1 K-quarter partials
  __shared__ __align__(16) float vd_s[16 * XS];     // v_d swizzled
  __shared__ __align__(16) float part_s[16];        // per-wave {den,num}
  __shared__ __align__(16) float yv_s[Tx];          // yv preloaded
  __shared__ float gates_s[1024];                   // f,o gates; epi partials
  __shared__ float dcfin_s[2 * Hx];                 // [d|c] fp32 (epilogue)
  __shared__ float l_s[Tx];                         // e (t=63) for beta
  __shared__ uint  beta2_s[Tx / 2];                 // beta packed f16 (t=63)
  __shared__ float e_s[Tx];                         // E_t
  __shared__ float red_s[4];
  __shared__ float ytil_s;
  __shared__ float den_s;
  __shared__ unsigned flagX, flagP, flagE;

  const int b   = blockIdx.x;
  const int tid = threadIdx.x;     // 0..1023
  const int h   = tid & 255;
  const int p   = tid >> 8;        // 0..3
  const int mq  = tid & 255;       // x1: output m
  const int qq  = tid >> 8;        // x1: K-quarter 0..3
  const size_t BM = (size_t)Bx * Mx;

  // ---- stage 0: W_d -> LDS (one-time), params, state, flags ----
  #pragma unroll
  for (int i = 0; i < 8; ++i) wdl[i * NT + tid] = Wd8q[i * NT + tid];
  if (tid < 256) vd_s[xsw(tid)] = v_d[tid];
  if (tid < 512) dsp_s[tid] = 0.0f;
  if (tid < 256) dsph_s[tid] = 0;
  if (tid < Tx) yv_s[tid] = yv[b * Tx + tid];
  if (tid == 0) { flagX = 0u; flagP = 0u; flagE = 0u; }

  float bj0 = 0.f, bj1 = 0.f;                  // gate waves
  if (tid < 512) { bj0 = b_ih[tid] + b_hh[tid]; bj1 = b_ih[tid + 512] + b_hh[tid + 512]; }
  float bWd_r = 0.f;                           // x1 quarter-0 threads (x2 fold)
  if (tid < 256) bWd_r = 2.0f * b_Wd[tid];
  float wih0 = 0.f, wih1 = 0.f, wih2 = 0.f, wih3 = 0.f;  // LSTM: threads 0-255
  if (tid < 256) {
    wih0 = W_ih[tid]; wih1 = W_ih[tid + 256]; wih2 = W_ih[tid + 512]; wih3 = W_ih[tid + 768];
  }
  const float wty = w_tilda[Mx];
  const float bwt = b_wt[0];

  // ---- stage 0b: E_t = sum_m w~_m enc[t][b][m] (one-time) ----
  if (tid < Tx) {
    const float* er = enc + (size_t)tid * BM + (size_t)b * Mx;
    float acc = 0.0f;
    for (int m = 0; m < Mx; m += 4) {
      float4 e4 = ld4(er + m);
      float4 w4 = ld4(w_tilda + m);
      acc += e4.x * w4.x + e4.y * w4.y + e4.z * w4.z + e4.w * w4.w;
    }
    e_s[tid] = acc;
  }

  // ---- stage 1: Y1[b] = enc[b] @ (2*U_d)^T (f16 weights) ----
  {
    const int n = h;
    const float* eb = enc + (size_t)b * Mx;
    for (int tb = p * 16; tb < p * 16 + 16; tb += 8) {
      f2v acc2[8];
      #pragma unroll
      for (int j = 0; j < 8; ++j) acc2[j] = f2v{0.f, 0.f};
      #pragma unroll 2
      for (int m8 = 0; m8 < 32; ++m8) {
        uint4 u = Ud8[m8 * 256 + n];
        f2v w01 = f2v{h2f((ushort)u.x), h2f((ushort)(u.x >> 16))};
        f2v w23 = f2v{h2f((ushort)u.y), h2f((ushort)(u.y >> 16))};
        f2v w45 = f2v{h2f((ushort)u.z), h2f((ushort)(u.z >> 16))};
        f2v w67 = f2v{h2f((ushort)u.w), h2f((ushort)(u.w >> 16))};
        #pragma unroll
        for (int j = 0; j < 8; ++j) {
          const float* ep = eb + (size_t)(tb + j) * BM + 8 * m8;
          float4 ea = ld4(ep), eb4 = ld4(ep + 4);
          acc2[j] += f2v{ea.x, ea.y} * w01;
          acc2[j] += f2v{ea.z, ea.w} * w23;
          acc2[j] += f2v{eb4.x, eb4.y} * w45;
          acc2[j] += f2v{eb4.z, eb4.w} * w67;
        }
      }
      #pragma unroll
      for (int j = 0; j < 8; ++j)
        Y1[((size_t)b * Tx + tb + j) * Mx + n] = f2h(acc2[j].x + acc2[j].y);
    }
  }
  __syncthreads();  // S1: wdl, dsp_s, dsph_s, vd_s, e_s, yv_s, flags, Y1

  // E[tq] per score thread (t-invariant): 1 register
  float e_r = 0.0f;
  if (tid >= 512) e_r = e_s[(tid - 512) >> 3];

  float sp_reg = 0.0f;   // LSTM state: threads 0-255

  for (int t = 0; t < Tx; ++t) {
    // ---- Y1 row segment prefetch (score waves; hidden under x1) ----
    uint4 yq0, yq1, yq2, yq3;
    if (tid >= 512) {
      const int idx = tid - 512;
      const int tq = idx >> 3, lq = idx & 7;
      const ushort* y1r = Y1 + ((size_t)b * Tx + tq) * Mx + lq * 32;
      yq0 = *(const uint4*)(y1r);
      yq1 = *(const uint4*)(y1r + 8);
      yq2 = *(const uint4*)(y1r + 16);
      yq3 = *(const uint4*)(y1r + 24);
    }

    // ===== x1: ALL 16 waves, K-quarter each (128 MACs, fp8 LDS) =====
    {
      f2v xa2 = f2v{0.f, 0.f};
      const uint4* xp = wdl + mq + (qq * 8) * 256;   // chunks qq*8..qq*8+7
      #pragma unroll
      for (int i = 0; i < 8; ++i) {
        uint4 u = xp[i * 256];
        const float4* ap = (const float4*)dsp_s + 4 * (qq * 8 + i);  // bcast
        float4 a0 = ap[0], a1 = ap[1], a2 = ap[2], a3 = ap[3];
        xa2 = dotq(u.x, a0, xa2); xa2 = dotq(u.y, a1, xa2);
        xa2 = dotq(u.z, a2, xa2); xa2 = dotq(u.w, a3, xa2);
      }
      // x2 folded for tanh: scale 0.125, bWd pre-doubled
      xq_s[qq * (16 * XS) + xsw(mq)] = (xa2.x + xa2.y) * 0.125f
                                     + (qq == 0 ? bWd_r : 0.0f);
    }
    __threadfence_block();
    if ((tid & 63) == 0)
      __hip_atomic_fetch_add(&flagX, 1u, __ATOMIC_RELEASE, __HIP_MEMORY_SCOPE_WORKGROUP);

    float gi = 0.0f, gg = 0.0f;   // own i,g gates (threads 0-255 keep in regs)
    if (tid < 512) {
      // ===== GATE WAVES: j=tid, j+512 via f16 fdot2 (no flagX wait) =====
      float ga0 = 0.f, ga1 = 0.f, gb0 = 0.f, gb1 = 0.f;
      const uint4* wp  = WhhH + tid;
      const uint4* adp = (const uint4*)dsph_s;       // 32 uint4 broadcast
      #pragma unroll 2
      for (int c = 0; c < 32; ++c) {
        uint4 wa = wp[c * 1024];
        uint4 wb = wp[c * 1024 + 512];
        uint4 a  = adp[c];                           // d[8c .. 8c+7] f16
        ga0 = dot2u(wa.x, a.x, ga0); ga1 = dot2u(wa.y, a.y, ga1);
        ga0 = dot2u(wa.z, a.z, ga0); ga1 = dot2u(wa.w, a.w, ga1);
        gb0 = dot2u(wb.x, a.x, gb0); gb1 = dot2u(wb.y, a.y, gb1);
        gb0 = dot2u(wb.z, a.z, gb0); gb1 = dot2u(wb.w, a.w, gb1);
      }
      gi = ga0 + ga1 + bj0;
      gg = gb0 + gb1 + bj1;
      if (tid >= 256) {
        // publish f (j=tid) and o (j=tid+512) gates for the LSTM threads
        gates_s[tid]       = gi;
        gates_s[tid + 512] = gg;
        __threadfence_block();
        if ((tid & 63) == 0)
          __hip_atomic_fetch_add(&flagE, 1u, __ATOMIC_RELEASE, __HIP_MEMORY_SCOPE_WORKGROUP);
      }
    } else {
      // ===== SCORE WAVES =====
      const int idx = tid - 512;               // 0..511
      const int tq = idx >> 3, lq = idx & 7;
      const unsigned tgtX = 16u * (unsigned)(t + 1);
      while (__hip_atomic_load(&flagX, __ATOMIC_ACQUIRE, __HIP_MEMORY_SCOPE_WORKGROUP) < tgtX) {}

      // scores: 8 lanes/query, lane covers 32 m's; sum 4 xq quarters
      float ps = 0.0f;
      {
        uint yy[8] = {yq0.x, yq0.y, yq0.z, yq0.w, yq1.x, yq1.y, yq1.z, yq1.w};
        uint zz[8] = {yq2.x, yq2.y, yq2.z, yq2.w, yq3.x, yq3.y, yq3.z, yq3.w};
        #pragma unroll
        for (int g = 0; g < 8; ++g) {
          const int c   = 2 * lq + (g >> 2);
          const int off = c * XS + 4 * (g & 3);
          float4 x0 = *(const float4*)(xq_s + off);
          float4 x1 = *(const float4*)(xq_s + 320 + off);
          float4 x2 = *(const float4*)(xq_s + 640 + off);
          float4 x3 = *(const float4*)(xq_s + 960 + off);
          float4 vv = *(const float4*)(vd_s + off);
          uint ya = (g < 4) ? yy[2 * g] : zz[2 * (g - 4)];
          uint yb = (g < 4) ? yy[2 * g + 1] : zz[2 * (g - 4) + 1];
          ps += tanh_pre(x0.x + x1.x + x2.x + x3.x + h2f((ushort)ya)) * vv.x
              + tanh_pre(x0.y + x1.y + x2.y + x3.y + h2f((ushort)(ya >> 16))) * vv.y
              + tanh_pre(x0.z + x1.z + x2.z + x3.z + h2f((ushort)yb)) * vv.z
              + tanh_pre(x0.w + x1.w + x2.w + x3.w + h2f((ushort)(yb >> 16))) * vv.w;
        }
        ps += __shfl_xor(ps, 1, 64);
        ps += __shfl_xor(ps, 2, 64);
        ps += __shfl_xor(ps, 4, 64);
      }
      // per-wave softmax partials: {den,num} over this wave's 8 queries
      {
        float e0 = __expf(ps);                 // |l|<=~10, fp32-safe
        float dp = (lq == 0) ? e0 : 0.0f;
        float np = dp * e_r;
        dp += __shfl_xor(dp, 8, 64);  np += __shfl_xor(np, 8, 64);
        dp += __shfl_xor(dp, 16, 64); np += __shfl_xor(np, 16, 64);
        dp += __shfl_xor(dp, 32, 64); np += __shfl_xor(np, 32, 64);
        const int wv = idx >> 6;               // score wave 0..7
        if ((idx & 63) == 0) { part_s[2 * wv] = dp; part_s[2 * wv + 1] = np; }
        if (t == Tx - 1 && lq == 0) l_s[tq] = e0;   // e for beta (t=63)
        __threadfence_block();
        if ((idx & 63) == 0)
          __hip_atomic_fetch_add(&flagP, 1u, __ATOMIC_RELEASE, __HIP_MEMORY_SCOPE_WORKGROUP);
      }

      if (idx == 0) {
        // ===== combiner (tid 512): 16-float sum -> ytil -> flagE =====
        __builtin_amdgcn_s_setprio(1);
        float yvt = yv_s[t];                   // issued before the spin
        const unsigned tgtP = 8u * (unsigned)(t + 1);
        while (__hip_atomic_load(&flagP, __ATOMIC_ACQUIRE, __HIP_MEMORY_SCOPE_WORKGROUP) < tgtP) {}
        float4 p0 = *(const float4*)(part_s);
        float4 p1 = *(const float4*)(part_s + 4);
        float4 p2 = *(const float4*)(part_s + 8);
        float4 p3 = *(const float4*)(part_s + 12);
        float den = (p0.x + p0.z) + (p1.x + p1.z) + (p2.x + p2.z) + (p3.x + p3.z);
        float num = (p0.y + p0.w) + (p1.y + p1.w) + (p2.y + p2.w) + (p3.y + p3.w);
        ytil_s = num * RCPF(den) + wty * yvt + bwt;
        if (t == Tx - 1) den_s = den;
        __threadfence_block();
        __hip_atomic_fetch_add(&flagE, 1u, __ATOMIC_RELEASE, __HIP_MEMORY_SCOPE_WORKGROUP);
        __builtin_amdgcn_s_setprio(0);
      }
    }

    // ===== LSTM cell: threads 0-255 (i,g in regs; f,o + ytil via flagE) ====
    if (tid < 256) {
      const unsigned tgtE = 5u * (unsigned)(t + 1);   // 4 gate pubs + combiner
      while (__hip_atomic_load(&flagE, __ATOMIC_ACQUIRE, __HIP_MEMORY_SCOPE_WORKGROUP) < tgtE) {}
      __builtin_amdgcn_s_setprio(1);
      const float ytil = ytil_s;
      float fi = sigm(gi                  + ytil * wih0);
      float ff = sigm(gates_s[256 + tid]  + ytil * wih1);
      float fg = tanh_fast(gg             + ytil * wih2);
      float fo = sigm(gates_s[768 + tid]  + ytil * wih3);
      float spn = ff * sp_reg + fi * fg;
      float dn  = fo * tanh_fast(spn);
      sp_reg = spn;
      dsp_s[tid]       = dn;
      dsp_s[256 + tid] = spn;
      dsph_s[tid]      = f2h(dn);          // packed f16 d for the gate fdot2
      if (t == Tx - 1) dcfin_s[tid] = dn;
      __builtin_amdgcn_s_setprio(0);
    }
    __syncthreads();  // B_state: d/sp(t) ready (single barrier per step)
  }

  // ---- beta(t=63) from saved e and den (one-time) ----
  if (tid >= 512 && tid < 576) {
    const int idx = tid - 512;
    float beta = l_s[idx] * RCPF(den_s);
    float bn = __shfl_xor(beta, 1, 64);
    if (!(idx & 1)) beta2_s[idx >> 1] = pk2(beta, bn);
  }
  __syncthreads();

  // ===== one-time context c (beta of t=63): threads >=512, 2 lanes per m ====
  if (tid >= 512) {
    const int idx = tid - 512;
    const int m = idx >> 1, q = idx & 1;
    float acc = 0.0f;
    #pragma unroll 4
    for (int j = 0; j < 32; ++j) {
      const int tt = q * 32 + j;
      uint bp = beta2_s[tt >> 1];
      float bb = (tt & 1) ? h2f((ushort)(bp >> 16)) : h2f((ushort)bp);
      acc += bb * enc[(size_t)tt * BM + (size_t)b * Mx + m];
    }
    acc += __shfl_xor(acc, 1, 64);
    if (q == 0) dcfin_s[256 + m] = acc;
  }
  __syncthreads();

  // ===== Epilogue: out[b] = v_y . (W_y @ [d|c] + b_Wy) + b_vy =====
  {
    float a = 0.0f;
    const float* wy = Wyt + h;
    for (int k = 128 * p; k < 128 * p + 128; ++k)
      a += wy[(size_t)k * 256] * dcfin_s[k];
    gates_s[p * 256 + h] = a;     // gates_s reused as epilogue partials
  }
  __syncthreads();
  if (tid < 256) {
    float aa = gates_s[h] + gates_s[256 + h] + gates_s[512 + h] + gates_s[768 + h]
             + b_Wy[h];
    float po = aa * v_y[h];
    po = wave_sum(po);
    if ((tid & 63) == 0) red_s[tid >> 6] = po;
  }
  __syncthreads();
  if (tid == 0) out[b] = red_s[0] + red_s[1] + red_s[2] + red_s[3] + b_vy[0];
}

extern "C" void kernel_launch(void* const* d_in, const int* in_sizes, int n_in,
                              void* d_out, int out_size, void* d_ws, size_t ws_size,
                              hipStream_t stream) {
  const float* enc     = (const float*)d_in[0];
  const float* yv      = (const float*)d_in[1];
  const float* W_d     = (const float*)d_in[2];
  const float* b_Wd    = (const float*)d_in[3];
  const float* U_d     = (const float*)d_in[4];
  const float* v_d     = (const float*)d_in[5];
  const float* w_tilda = (const float*)d_in[6];
  const float* b_wt    = (const float*)d_in[7];
  const float* W_ih    = (const float*)d_in[8];
  const float* W_hh    = (const float*)d_in[9];
  const float* b_ih    = (const float*)d_in[10];
  const float* b_hh    = (const float*)d_in[11];
  const float* W_y     = (const float*)d_in[12];
  const float* b_Wy    = (const float*)d_in[13];
  const float* v_y     = (const float*)d_in[14];
  const float* b_vy    = (const float*)d_in[15];
  float* outp = (float*)d_out;

  char* ws = (char*)d_ws;
  uint4* WhhH  = (uint4*)ws;                               // 512 KB f16
  uint4* Wd8q  = (uint4*)(ws + (512 << 10));               // 128 KB
  uint4* Ud8   = (uint4*)(ws + (640 << 10));               // 128 KB
  float* Wyt   = (float*)(ws + (768 << 10));               // 512 KB
  ushort* Y1   = (ushort*)(ws + (1280 << 10));             // 8 MB

  const int DYN_LDS = 128 << 10;   // W_d fp8 slab in dynamic LDS
  hipFuncSetAttribute((const void*)fused,
                      hipFuncAttributeMaxDynamicSharedMemorySize, DYN_LDS);

  hipLaunchKernelGGL(pack_weights, dim3(224), dim3(256), 0, stream,
                     W_d, W_hh, U_d, W_y, WhhH, Wd8q, Ud8, Wyt);
  hipLaunchKernelGGL(fused, dim3(Bx), dim3(NT), DYN_LDS, stream,
                     enc, yv, b_Wd, v_d, w_tilda, b_wt, W_ih, b_ih, b_hh,
                     b_Wy, v_y, b_vy, WhhH, Wd8q, Ud8, Wyt, Y1, outp);
}

// Round 13
// 572.123 us; speedup vs baseline: 1.0286x; 1.0027x over previous
//
#include <hip/hip_runtime.h>

// ---------------------------------------------------------------------------
// TemporalAttnLayer: B=256, T=64, M=256, H=256
//
// Round-25 = Round-23 EXACTLY (546 us rocprof best; r24's distributed
// softmax regressed +12 us - parallelizing the softmax added more sync than
// it removed) + the one never-isolated zero-register lever:
//  - s_sleep(1) in the flagX spin (8 score waves poll while the last x1
//    waves finish LDS-heavy work) and the flagE spin (4 LSTM waves poll
//    while softmax + gate pubs run). Backoff removes ~10x the flag-poll
//    LDS traffic in the two highest-contention windows; wake-latency cost
//    <= ~64 cy per spin per step (~0.6%).
//  - flagL spin (1 wave) stays plain: wake latency directly on the chain.
// Everything else byte-identical to r23 (K4 x1 on 16 waves, f16 fdot2
// gates no-wait, wave-8 merged softmax, LSTM threads 0-255 flagE=5,
// single barrier). Spill gate: WRITE > 15 MB. Neutral => r23 is the plateau.
// ---------------------------------------------------------------------------

#define Bx 256
#define Tx 64
#define Mx 256
#define Hx 256
#define NT 1024
#define XS 20     // swizzle chunk stride (floats) for xq/vd

typedef unsigned int  uint;
typedef unsigned short ushort;
typedef _Float16 h2  __attribute__((ext_vector_type(2)));
typedef float    f2v __attribute__((ext_vector_type(2)));

__device__ __forceinline__ float4 ld4(const float* p) { return *(const float4*)p; }
__device__ __forceinline__ float h2f(ushort s) {
  union { ushort s; _Float16 h; } c; c.s = s; return (float)c.h;
}
__device__ __forceinline__ ushort f2h(float f) {
  union { _Float16 h; ushort s; } c; c.h = (_Float16)f; return c.s;
}
__device__ __forceinline__ uint pk2(float a, float b) {
  return (uint)f2h(a) | ((uint)f2h(b) << 16);
}

#if defined(__has_builtin)
#if __has_builtin(__builtin_amdgcn_rcpf)
#define RCPF(x) __builtin_amdgcn_rcpf(x)
#endif
#if __has_builtin(__builtin_amdgcn_fdot2)
#define HAVE_FDOT2 1
#endif
#if __has_builtin(__builtin_amdgcn_cvt_pk_f32_fp8) && __has_builtin(__builtin_amdgcn_cvt_pk_fp8_f32)
#define HAVE_FP8 1
#endif
#endif
#ifndef RCPF
#define RCPF(x) (1.0f / (x))
#endif

__device__ __forceinline__ float tanh_fast(float x) {
  float e2 = __expf(2.0f * x);
  return 1.0f - 2.0f * RCPF(e2 + 1.0f);
}
// arg already pre-doubled upstream: tanh(x) where z2 = 2x
__device__ __forceinline__ float tanh_pre(float z2) {
  return 1.0f - 2.0f * RCPF(__expf(z2) + 1.0f);
}
__device__ __forceinline__ float sigm(float x) {
  return RCPF(1.0f + __expf(-x));
}
__device__ __forceinline__ float wave_sum(float v) {
  #pragma unroll
  for (int o = 1; o < 64; o <<= 1) v += __shfl_xor(v, o, 64);
  return v;
}
__device__ __forceinline__ int xsw(int m) { return (m >> 4) * XS + (m & 15); }

// f16 pair dot: acc += w.lo*a.lo + w.hi*a.hi (single v_dot2_f32_f16)
__device__ __forceinline__ float dot2u(uint w, uint a, float acc) {
#ifdef HAVE_FDOT2
  h2 W = __builtin_bit_cast(h2, w);
  h2 A = __builtin_bit_cast(h2, a);
  return __builtin_amdgcn_fdot2(W, A, acc, false);
#else
  return acc + h2f((ushort)w) * h2f((ushort)a)
             + h2f((ushort)(w >> 16)) * h2f((ushort)(a >> 16));
#endif
}

// ---- fp8 e4m3fn encode/decode (HW path + software fallback) ----
__device__ __forceinline__ uint sw8(float f) {
  union { float f; uint u; } c; c.f = f;
  uint s = (c.u >> 31) << 7;
  float a = fabsf(f);
  if (!(a >= 0.0009765625f)) return s;
  if (a >= 448.f) return s | 0x7e;
  int e = (int)((c.u >> 23) & 0xff) - 127;
  if (e < -6) { int q = (int)(a * 512.f + 0.5f); return s | (uint)q; }
  uint m = ((c.u & 0x7fffff) + 0x80000) >> 20;
  if (m == 8) { m = 0; ++e; }
  if (e > 8) return s | 0x7e;
  return s | ((uint)(e + 7) << 3) | m;
}
__device__ __forceinline__ float sw8d(uint b) {
  uint s = b >> 7, e = (b >> 3) & 0xf, m = b & 7;
  float v;
  if (e) { union { uint u; float f; } c; c.u = ((e + 120u) << 23) | (m << 20); v = c.f; }
  else v = (float)m * 0.001953125f;
  return s ? -v : v;
}
__device__ __forceinline__ uint pk_fp8x4(float w0, float w1, float w2, float w3) {
#ifdef HAVE_FP8
  int u = 0;
  u = __builtin_amdgcn_cvt_pk_fp8_f32(w0, w1, u, false);
  u = __builtin_amdgcn_cvt_pk_fp8_f32(w2, w3, u, true);
  return (uint)u;
#else
  return sw8(w0) | (sw8(w1) << 8) | (sw8(w2) << 16) | (sw8(w3) << 24);
#endif
}
template <bool HI>
__device__ __forceinline__ f2v dec2(uint w) {
#ifdef HAVE_FP8
  return __builtin_amdgcn_cvt_pk_f32_fp8((int)w, HI);
#else
  uint b0 = HI ? ((w >> 16) & 0xffu) : (w & 0xffu);
  uint b1 = HI ? (w >> 24) : ((w >> 8) & 0xffu);
  return f2v{sw8d(b0), sw8d(b1)};
#endif
}
__device__ __forceinline__ f2v dotq(uint w, float4 a, f2v acc) {
  acc += dec2<false>(w) * f2v{a.x, a.y};
  acc += dec2<true>(w)  * f2v{a.z, a.w};
  return acc;
}

// ---------------------------------------------------------------------------
// Pack kernel (identical to r22/r23).
// ---------------------------------------------------------------------------
__global__ __launch_bounds__(256)
void pack_weights(const float* __restrict__ W_d,
                  const float* __restrict__ W_hh,
                  const float* __restrict__ U_d,
                  const float* __restrict__ W_y,
                  uint4* __restrict__ WhhH,
                  uint4* __restrict__ Wd8q,
                  uint4* __restrict__ Ud8,
                  float* __restrict__ Wyt) {
  const int blk = blockIdx.x, tid = threadIdx.x;
  if (blk < 32) {                        // WhhH chunk c: cols 8c..8c+7
    const int c = blk;
    #pragma unroll
    for (int q = 0; q < 4; ++q) {
      const int j = tid + 256 * q;
      const float* wr = W_hh + (size_t)j * 256 + 8 * c;
      float4 a = ld4(wr), b = ld4(wr + 4);
      WhhH[c * 1024 + j] = uint4{pk2(a.x, a.y), pk2(a.z, a.w),
                                 pk2(b.x, b.y), pk2(b.z, b.w)};
    }
  } else if (blk < 64) {                 // Wd8q
    const int k16 = blk - 32;
    const float* wr = W_d + (size_t)tid * 512 + 16 * k16;
    float4 a = ld4(wr), b = ld4(wr + 4), c = ld4(wr + 8), d = ld4(wr + 12);
    uint4 u;
    u.x = pk_fp8x4(16.f * a.x, 16.f * a.y, 16.f * a.z, 16.f * a.w);
    u.y = pk_fp8x4(16.f * b.x, 16.f * b.y, 16.f * b.z, 16.f * b.w);
    u.z = pk_fp8x4(16.f * c.x, 16.f * c.y, 16.f * c.z, 16.f * c.w);
    u.w = pk_fp8x4(16.f * d.x, 16.f * d.y, 16.f * d.z, 16.f * d.w);
    Wd8q[k16 * 256 + tid] = u;
  } else if (blk < 96) {                 // Ud8 (f16, x2 folded for tanh)
    const int m8 = blk - 64;
    float4 a = ld4(U_d + (size_t)tid * 256 + 8 * m8);
    float4 b = ld4(U_d + (size_t)tid * 256 + 8 * m8 + 4);
    Ud8[m8 * 256 + tid] = uint4{pk2(2.f * a.x, 2.f * a.y), pk2(2.f * a.z, 2.f * a.w),
                                pk2(2.f * b.x, 2.f * b.y), pk2(2.f * b.z, 2.f * b.w)};
  } else {                               // Wyt transpose
    const int k0 = (blk - 96) * 4;
    float4 w = ld4(W_y + (size_t)tid * 512 + k0);
    Wyt[(k0 + 0) * 256 + tid] = w.x;
    Wyt[(k0 + 1) * 256 + tid] = w.y;
    Wyt[(k0 + 2) * 256 + tid] = w.z;
    Wyt[(k0 + 3) * 256 + tid] = w.w;
  }
}

// ---------------------------------------------------------------------------
// Main kernel: one 1024-thread wg per batch element.
// Per step: ALL 16 waves x1 K-quarter -> flagX add -> {gate waves: f16
// fdot2 gates (no flagX wait) | score waves: wait flagX=16 (s_sleep) ->
// scores -> flagL -> wave 8 softmax -> flagE} -> LSTM (threads 0-255,
// flagE=5, s_sleep) -> single barrier.
// ---------------------------------------------------------------------------
__global__ __launch_bounds__(NT, 1)
void fused(const float* __restrict__ enc,      // (T,B,M)
           const float* __restrict__ yv,       // (B,T,1)
           const float* __restrict__ b_Wd,     // (M)
           const float* __restrict__ v_d,      // (1,M)
           const float* __restrict__ w_tilda,  // (1,M+1)
           const float* __restrict__ b_wt,     // (1)
           const float* __restrict__ W_ih,     // (4H,1)
           const float* __restrict__ b_ih,     // (4H)
           const float* __restrict__ b_hh,     // (4H)
           const float* __restrict__ b_Wy,     // (H)
           const float* __restrict__ v_y,      // (1,H)
           const float* __restrict__ b_vy,     // (1)
           const uint4* __restrict__ WhhH,
           const uint4* __restrict__ Wd8q,
           const uint4* __restrict__ Ud8,
           const float* __restrict__ Wyt,
           ushort* __restrict__ Y1,            // (B,T,M) f16 scratch
           float* __restrict__ out)            // (B,1)
{
  extern __shared__ __align__(16) uint4 wdl[];      // 8192 uint4 = 128 KB W_d
  __shared__ __align__(16) float dsp_s[2 * Hx];     // [d|sp] f32 (x1 bcast)
  __shared__ __align__(16) ushort dsph_s[Hx];       // d packed f16 (gates)
  __shared__ __align__(16) float xq_s[4 * 16 * XS]; // x1 K-quarter partials
  __shared__ __align__(16) float vd_s[16 * XS];     // v_d swizzled
  __shared__ float gates_s[1024];                   // f,o gates; epi partials
  __shared__ float dcfin_s[2 * Hx];                 // [d|c] fp32 (epilogue)
  __shared__ float l_s[Tx];
  __shared__ uint  beta2_s[Tx / 2];                 // beta packed f16 (t=63)
  __shared__ float e_s[Tx];                         // E_t
  __shared__ float red_s[4];
  __shared__ float ytil_s;
  __shared__ unsigned flagX, flagL, flagE;

  const int b   = blockIdx.x;
  const int tid = threadIdx.x;     // 0..1023
  const int h   = tid & 255;
  const int p   = tid >> 8;        // 0..3
  const int mq  = tid & 255;       // x1: output m
  const int qq  = tid >> 8;        // x1: K-quarter 0..3
  const size_t BM = (size_t)Bx * Mx;

  // ---- stage 0: W_d -> LDS (one-time), params, state, flags ----
  #pragma unroll
  for (int i = 0; i < 8; ++i) wdl[i * NT + tid] = Wd8q[i * NT + tid];
  if (tid < 256) vd_s[xsw(tid)] = v_d[tid];
  if (tid < 512) dsp_s[tid] = 0.0f;
  if (tid < 256) dsph_s[tid] = 0;
  if (tid == 0) { flagX = 0u; flagL = 0u; flagE = 0u; }

  float bj0 = 0.f, bj1 = 0.f;                  // gate waves
  if (tid < 512) { bj0 = b_ih[tid] + b_hh[tid]; bj1 = b_ih[tid + 512] + b_hh[tid + 512]; }
  float bWd_r = 0.f;                           // x1 quarter-0 threads (x2 fold)
  if (tid < 256) bWd_r = 2.0f * b_Wd[tid];
  float wih0 = 0.f, wih1 = 0.f, wih2 = 0.f, wih3 = 0.f;  // LSTM: threads 0-255
  if (tid < 256) {
    wih0 = W_ih[tid]; wih1 = W_ih[tid + 256]; wih2 = W_ih[tid + 512]; wih3 = W_ih[tid + 768];
  }
  float yv_r = 0.f;                            // softmax wave
  if (tid >= 512 && tid < 576) yv_r = yv[b * Tx + (tid - 512)];
  const float wty = w_tilda[Mx];
  const float bwt = b_wt[0];

  // ---- stage 0b: E_t = sum_m w~_m enc[t][b][m] (one-time) ----
  if (tid < Tx) {
    const float* er = enc + (size_t)tid * BM + (size_t)b * Mx;
    float acc = 0.0f;
    for (int m = 0; m < Mx; m += 4) {
      float4 e4 = ld4(er + m);
      float4 w4 = ld4(w_tilda + m);
      acc += e4.x * w4.x + e4.y * w4.y + e4.z * w4.z + e4.w * w4.w;
    }
    e_s[tid] = acc;
  }

  // ---- stage 1: Y1[b] = enc[b] @ (2*U_d)^T (f16 weights) ----
  {
    const int n = h;
    const float* eb = enc + (size_t)b * Mx;
    for (int tb = p * 16; tb < p * 16 + 16; tb += 8) {
      f2v acc2[8];
      #pragma unroll
      for (int j = 0; j < 8; ++j) acc2[j] = f2v{0.f, 0.f};
      #pragma unroll 2
      for (int m8 = 0; m8 < 32; ++m8) {
        uint4 u = Ud8[m8 * 256 + n];
        f2v w01 = f2v{h2f((ushort)u.x), h2f((ushort)(u.x >> 16))};
        f2v w23 = f2v{h2f((ushort)u.y), h2f((ushort)(u.y >> 16))};
        f2v w45 = f2v{h2f((ushort)u.z), h2f((ushort)(u.z >> 16))};
        f2v w67 = f2v{h2f((ushort)u.w), h2f((ushort)(u.w >> 16))};
        #pragma unroll
        for (int j = 0; j < 8; ++j) {
          const float* ep = eb + (size_t)(tb + j) * BM + 8 * m8;
          float4 ea = ld4(ep), eb4 = ld4(ep + 4);
          acc2[j] += f2v{ea.x, ea.y} * w01;
          acc2[j] += f2v{ea.z, ea.w} * w23;
          acc2[j] += f2v{eb4.x, eb4.y} * w45;
          acc2[j] += f2v{eb4.z, eb4.w} * w67;
        }
      }
      #pragma unroll
      for (int j = 0; j < 8; ++j)
        Y1[((size_t)b * Tx + tb + j) * Mx + n] = f2h(acc2[j].x + acc2[j].y);
    }
  }
  __syncthreads();  // S1: wdl, dsp_s, dsph_s, vd_s, e_s, flags, Y1 ready

  // e_s row for the softmax wave: 1 register
  float e_r = 0.0f;
  if (tid >= 512 && tid < 576) e_r = e_s[tid - 512];

  float sp_reg = 0.0f;   // LSTM state: threads 0-255

  for (int t = 0; t < Tx; ++t) {
    // ---- Y1 row segment prefetch (score waves; hidden under x1) ----
    uint4 yq0, yq1, yq2, yq3;
    if (tid >= 512) {
      const int idx = tid - 512;
      const int tq = idx >> 3, lq = idx & 7;
      const ushort* y1r = Y1 + ((size_t)b * Tx + tq) * Mx + lq * 32;
      yq0 = *(const uint4*)(y1r);
      yq1 = *(const uint4*)(y1r + 8);
      yq2 = *(const uint4*)(y1r + 16);
      yq3 = *(const uint4*)(y1r + 24);
    }

    // ===== x1: ALL 16 waves, K-quarter each (128 MACs, fp8 LDS) =====
    {
      f2v xa2 = f2v{0.f, 0.f};
      const uint4* xp = wdl + mq + (qq * 8) * 256;   // chunks qq*8..qq*8+7
      #pragma unroll
      for (int i = 0; i < 8; ++i) {
        uint4 u = xp[i * 256];
        const float4* ap = (const float4*)dsp_s + 4 * (qq * 8 + i);  // bcast
        float4 a0 = ap[0], a1 = ap[1], a2 = ap[2], a3 = ap[3];
        xa2 = dotq(u.x, a0, xa2); xa2 = dotq(u.y, a1, xa2);
        xa2 = dotq(u.z, a2, xa2); xa2 = dotq(u.w, a3, xa2);
      }
      // x2 folded for tanh: scale 0.125, bWd pre-doubled
      xq_s[qq * (16 * XS) + xsw(mq)] = (xa2.x + xa2.y) * 0.125f
                                     + (qq == 0 ? bWd_r : 0.0f);
    }
    __threadfence_block();
    if ((tid & 63) == 0)
      __hip_atomic_fetch_add(&flagX, 1u, __ATOMIC_RELEASE, __HIP_MEMORY_SCOPE_WORKGROUP);

    float gi = 0.0f, gg = 0.0f;   // own i,g gates (threads 0-255 keep in regs)
    if (tid < 512) {
      // ===== GATE WAVES: j=tid, j+512 via f16 fdot2 (no flagX wait) =====
      float ga0 = 0.f, ga1 = 0.f, gb0 = 0.f, gb1 = 0.f;
      const uint4* wp  = WhhH + tid;
      const uint4* adp = (const uint4*)dsph_s;       // 32 uint4 broadcast
      #pragma unroll 2
      for (int c = 0; c < 32; ++c) {
        uint4 wa = wp[c * 1024];
        uint4 wb = wp[c * 1024 + 512];
        uint4 a  = adp[c];                           // d[8c .. 8c+7] f16
        ga0 = dot2u(wa.x, a.x, ga0); ga1 = dot2u(wa.y, a.y, ga1);
        ga0 = dot2u(wa.z, a.z, ga0); ga1 = dot2u(wa.w, a.w, ga1);
        gb0 = dot2u(wb.x, a.x, gb0); gb1 = dot2u(wb.y, a.y, gb1);
        gb0 = dot2u(wb.z, a.z, gb0); gb1 = dot2u(wb.w, a.w, gb1);
      }
      gi = ga0 + ga1 + bj0;
      gg = gb0 + gb1 + bj1;
      if (tid >= 256) {
        // publish f (j=tid) and o (j=tid+512) gates for the LSTM threads
        gates_s[tid]       = gi;
        gates_s[tid + 512] = gg;
        __threadfence_block();
        if ((tid & 63) == 0)
          __hip_atomic_fetch_add(&flagE, 1u, __ATOMIC_RELEASE, __HIP_MEMORY_SCOPE_WORKGROUP);
      }
    } else {
      // ===== SCORE WAVES =====
      const int idx = tid - 512;               // 0..511
      const int tq = idx >> 3, lq = idx & 7;
      const unsigned tgtX = 16u * (unsigned)(t + 1);
      while (__hip_atomic_load(&flagX, __ATOMIC_ACQUIRE, __HIP_MEMORY_SCOPE_WORKGROUP) < tgtX)
        __builtin_amdgcn_s_sleep(1);   // back off: last x1 waves are LDS-busy

      // scores: 8 lanes/query, lane covers 32 m's; sum 4 xq quarters
      {
        float ps = 0.0f;
        uint yy[8] = {yq0.x, yq0.y, yq0.z, yq0.w, yq1.x, yq1.y, yq1.z, yq1.w};
        uint zz[8] = {yq2.x, yq2.y, yq2.z, yq2.w, yq3.x, yq3.y, yq3.z, yq3.w};
        #pragma unroll
        for (int g = 0; g < 8; ++g) {
          const int c   = 2 * lq + (g >> 2);
          const int off = c * XS + 4 * (g & 3);
          float4 x0 = *(const float4*)(xq_s + off);
          float4 x1 = *(const float4*)(xq_s + 320 + off);
          float4 x2 = *(const float4*)(xq_s + 640 + off);
          float4 x3 = *(const float4*)(xq_s + 960 + off);
          float4 vv = *(const float4*)(vd_s + off);
          uint ya = (g < 4) ? yy[2 * g] : zz[2 * (g - 4)];
          uint yb = (g < 4) ? yy[2 * g + 1] : zz[2 * (g - 4) + 1];
          ps += tanh_pre(x0.x + x1.x + x2.x + x3.x + h2f((ushort)ya)) * vv.x
              + tanh_pre(x0.y + x1.y + x2.y + x3.y + h2f((ushort)(ya >> 16))) * vv.y
              + tanh_pre(x0.z + x1.z + x2.z + x3.z + h2f((ushort)yb)) * vv.z
              + tanh_pre(x0.w + x1.w + x2.w + x3.w + h2f((ushort)(yb >> 16))) * vv.w;
        }
        ps += __shfl_xor(ps, 1, 64);
        ps += __shfl_xor(ps, 2, 64);
        ps += __shfl_xor(ps, 4, 64);
        if (lq == 0) l_s[tq] = ps;
      }
      __threadfence_block();
      if ((tid & 63) == 0)
        __hip_atomic_fetch_add(&flagL, 1u, __ATOMIC_RELEASE, __HIP_MEMORY_SCOPE_WORKGROUP);

      if (idx < 64) {
        // merged softmax+ytil (wave 8): |l| <= ~10 so no max-sub needed;
        // one interleaved {den,num} reduction; beta only at t==63.
        __builtin_amdgcn_s_setprio(1);
        const unsigned tgtL = 8u * (unsigned)(t + 1);
        while (__hip_atomic_load(&flagL, __ATOMIC_ACQUIRE, __HIP_MEMORY_SCOPE_WORKGROUP) < tgtL) {}
        float e0  = __expf(l_s[idx]);
        float den = e0;
        float num = e0 * e_r;
        #pragma unroll
        for (int o = 1; o < 64; o <<= 1) {
          den += __shfl_xor(den, o, 64);
          num += __shfl_xor(num, o, 64);
        }
        if (t == Tx - 1) {
          float beta = e0 * RCPF(den);
          float bn = __shfl_xor(beta, 1, 64);
          if (!(idx & 1)) beta2_s[idx >> 1] = pk2(beta, bn);
        }
        if (idx == t) ytil_s = num * RCPF(den) + wty * yv_r + bwt;
        __threadfence_block();
        if (idx == 0)
          __hip_atomic_fetch_add(&flagE, 1u, __ATOMIC_RELEASE, __HIP_MEMORY_SCOPE_WORKGROUP);
        __builtin_amdgcn_s_setprio(0);
      }
    }

    // ===== LSTM cell: threads 0-255 (i,g in regs; f,o + ytil via flagE) ====
    if (tid < 256) {
      const unsigned tgtE = 5u * (unsigned)(t + 1);
      while (__hip_atomic_load(&flagE, __ATOMIC_ACQUIRE, __HIP_MEMORY_SCOPE_WORKGROUP) < tgtE)
        __builtin_amdgcn_s_sleep(1);   // back off: softmax wave is LDS-busy
      __builtin_amdgcn_s_setprio(1);
      const float ytil = ytil_s;
      float fi = sigm(gi                  + ytil * wih0);
      float ff = sigm(gates_s[256 + tid]  + ytil * wih1);
      float fg = tanh_fast(gg             + ytil * wih2);
      float fo = sigm(gates_s[768 + tid]  + ytil * wih3);
      float spn = ff * sp_reg + fi * fg;
      float dn  = fo * tanh_fast(spn);
      sp_reg = spn;
      dsp_s[tid]       = dn;
      dsp_s[256 + tid] = spn;
      dsph_s[tid]      = f2h(dn);          // packed f16 d for the gate fdot2
      if (t == Tx - 1) dcfin_s[tid] = dn;
      __builtin_amdgcn_s_setprio(0);
    }
    __syncthreads();  // B_state: d/sp(t) ready (single barrier per step)
  }

  // ===== one-time context c (beta of t=63): threads >=512, 2 lanes per m ====
  if (tid >= 512) {
    const int idx = tid - 512;
    const int m = idx >> 1, q = idx & 1;
    float acc = 0.0f;
    #pragma unroll 4
    for (int j = 0; j < 32; ++j) {
      const int tt = q * 32 + j;
      uint bp = beta2_s[tt >> 1];
      float bb = (tt & 1) ? h2f((ushort)(bp >> 16)) : h2f((ushort)bp);
      acc += bb * enc[(size_t)tt * BM + (size_t)b * Mx + m];
    }
    acc += __shfl_xor(acc, 1, 64);
    if (q == 0) dcfin_s[256 + m] = acc;
  }
  __syncthreads();

  // ===== Epilogue: out[b] = v_y . (W_y @ [d|c] + b_Wy) + b_vy =====
  {
    float a = 0.0f;
    const float* wy = Wyt + h;
    for (int k = 128 * p; k < 128 * p + 128; ++k)
      a += wy[(size_t)k * 256] * dcfin_s[k];
    gates_s[p * 256 + h] = a;     // gates_s reused as epilogue partials
  }
  __syncthreads();
  if (tid < 256) {
    float aa = gates_s[h] + gates_s[256 + h] + gates_s[512 + h] + gates_s[768 + h]
             + b_Wy[h];
    float po = aa * v_y[h];
    po = wave_sum(po);
    if ((tid & 63) == 0) red_s[tid >> 6] = po;
  }
  __syncthreads();
  if (tid == 0) out[b] = red_s[0] + red_s[1] + red_s[2] + red_s[3] + b_vy[0];
}

extern "C" void kernel_launch(void* const* d_in, const int* in_sizes, int n_in,
                              void* d_out, int out_size, void* d_ws, size_t ws_size,
                              hipStream_t stream) {
  const float* enc     = (const float*)d_in[0];
  const float* yv      = (const float*)d_in[1];
  const float* W_d     = (const float*)d_in[2];
  const float* b_Wd    = (const float*)d_in[3];
  const float* U_d     = (const float*)d_in[4];
  const float* v_d     = (const float*)d_in[5];
  const float* w_tilda = (const float*)d_in[6];
  const float* b_wt    = (const float*)d_in[7];
  const float* W_ih    = (const float*)d_in[8];
  const float* W_hh    = (const float*)d_in[9];
  const float* b_ih    = (const float*)d_in[10];
  const float* b_hh    = (const float*)d_in[11];
  const float* W_y     = (const float*)d_in[12];
  const float* b_Wy    = (const float*)d_in[13];
  const float* v_y     = (const float*)d_in[14];
  const float* b_vy    = (const float*)d_in[15];
  float* outp = (float*)d_out;

  char* ws = (char*)d_ws;
  uint4* WhhH  = (uint4*)ws;                               // 512 KB f16
  uint4* Wd8q  = (uint4*)(ws + (512 << 10));               // 128 KB
  uint4* Ud8   = (uint4*)(ws + (640 << 10));               // 128 KB
  float* Wyt   = (float*)(ws + (768 << 10));               // 512 KB
  ushort* Y1   = (ushort*)(ws + (1280 << 10));             // 8 MB

  const int DYN_LDS = 128 << 10;   // W_d fp8 slab in dynamic LDS
  hipFuncSetAttribute((const void*)fused,
                      hipFuncAttributeMaxDynamicSharedMemorySize, DYN_LDS);

  hipLaunchKernelGGL(pack_weights, dim3(224), dim3(256), 0, stream,
                     W_d, W_hh, U_d, W_y, WhhH, Wd8q, Ud8, Wyt);
  hipLaunchKernelGGL(fused, dim3(Bx), dim3(NT), DYN_LDS, stream,
                     enc, yv, b_Wd, v_d, w_tilda, b_wt, W_ih, b_ih, b_hh,
                     b_Wy, v_y, b_vy, WhhH, Wd8q, Ud8, Wyt, Y1, outp);
}